// Round 1
// baseline (1749.308 us; speedup 1.0000x reference)
//
#include <hip/hip_runtime.h>
#include <stdint.h>

#define B_   4096
#define S_   544
#define H_   256
#define D_   128
#define M_   50000
#define KNN  50
#define NSLICE 8
#define SLICE_LEN (M_ / NSLICE)   // 6250
#define CAP  128

typedef unsigned long long u64;
typedef unsigned int u32;

// ---------------- K1: h = relu(states@W1+b1) (z=0), v1 = relu(states@V1+c1) (z=1) ----
__global__ __launch_bounds__(256) void k1_gemm(
    const float* __restrict__ A,
    const float* __restrict__ W1, const float* __restrict__ b1,
    const float* __restrict__ V1, const float* __restrict__ c1,
    float* __restrict__ hout, float* __restrict__ v1out)
{
  const float* W    = (blockIdx.z == 0) ? W1 : V1;
  const float* bias = (blockIdx.z == 0) ? b1 : c1;
  float* out        = (blockIdx.z == 0) ? hout : v1out;

  __shared__ float as[16][68];
  __shared__ float bs[16][64];

  int tid = threadIdx.x;
  int tx = tid & 15, ty = tid >> 4;
  int rb = blockIdx.y * 64, cb = blockIdx.x * 64;

  float acc[4][4] = {};

  for (int k0 = 0; k0 < S_; k0 += 16) {
    {
      int r = tid >> 2, k4 = (tid & 3) << 2;
      float4 a = *(const float4*)&A[(size_t)(rb + r) * S_ + k0 + k4];
      as[k4 + 0][r] = a.x; as[k4 + 1][r] = a.y;
      as[k4 + 2][r] = a.z; as[k4 + 3][r] = a.w;
    }
    {
      int kk = tid >> 4, c4 = (tid & 15) << 2;
      *(float4*)&bs[kk][c4] = *(const float4*)&W[(size_t)(k0 + kk) * H_ + cb + c4];
    }
    __syncthreads();
#pragma unroll
    for (int kk = 0; kk < 16; ++kk) {
      float4 a4 = *(const float4*)&as[kk][ty << 2];
      float4 b4 = *(const float4*)&bs[kk][tx << 2];
      float av[4] = {a4.x, a4.y, a4.z, a4.w};
      float bv[4] = {b4.x, b4.y, b4.z, b4.w};
#pragma unroll
      for (int i = 0; i < 4; ++i)
#pragma unroll
        for (int j = 0; j < 4; ++j)
          acc[i][j] = fmaf(av[i], bv[j], acc[i][j]);
    }
    __syncthreads();
  }

#pragma unroll
  for (int i = 0; i < 4; ++i) {
    int r = rb + (ty << 2) + i;
#pragma unroll
    for (int j = 0; j < 4; ++j) {
      int c = cb + (tx << 2) + j;
      float v = acc[i][j] + bias[c];
      out[(size_t)r * H_ + c] = v > 0.0f ? v : 0.0f;
    }
  }
}

// ---------------- K2: mode 0: q = LN(h@W2+b2), q2 = sum(q*q)
//                      mode 1: v2 = relu(v1@V2+c2); net = v2@V3 + c3 ------------------
__global__ __launch_bounds__(256) void k2_fused(
    int mode,
    const float* __restrict__ A,      // [B_][H_]
    const float* __restrict__ W,      // [H_][D_]
    const float* __restrict__ bias,   // [D_]
    const float* __restrict__ lng, const float* __restrict__ lnb,
    const float* __restrict__ V3, const float* __restrict__ c3,
    float* __restrict__ qout, float* __restrict__ q2out,
    float* __restrict__ netout)
{
  __shared__ float as[32][36];
  __shared__ float bs[32][132];
  __shared__ float yt[32][132];
  __shared__ float v3s[128];

  int tid = threadIdx.x;
  int tx = tid & 31, ty = tid >> 5;
  int rb = blockIdx.x * 32;

  if (mode == 1 && tid < 128) v3s[tid] = V3[tid];

  float acc[4][4] = {};

  for (int k0 = 0; k0 < H_; k0 += 32) {
    {
      int r = tid >> 3, k4 = (tid & 7) << 2;
      float4 a = *(const float4*)&A[(size_t)(rb + r) * H_ + k0 + k4];
      as[k4 + 0][r] = a.x; as[k4 + 1][r] = a.y;
      as[k4 + 2][r] = a.z; as[k4 + 3][r] = a.w;
    }
    {
      int kk = tid >> 3, c16 = (tid & 7) << 4;
#pragma unroll
      for (int t = 0; t < 4; ++t)
        *(float4*)&bs[kk][c16 + (t << 2)] =
            *(const float4*)&W[(size_t)(k0 + kk) * D_ + c16 + (t << 2)];
    }
    __syncthreads();
#pragma unroll
    for (int kk = 0; kk < 32; ++kk) {
      float4 a4 = *(const float4*)&as[kk][ty << 2];
      float4 b4 = *(const float4*)&bs[kk][tx << 2];
      float av[4] = {a4.x, a4.y, a4.z, a4.w};
      float bv[4] = {b4.x, b4.y, b4.z, b4.w};
#pragma unroll
      for (int i = 0; i < 4; ++i)
#pragma unroll
        for (int j = 0; j < 4; ++j)
          acc[i][j] = fmaf(av[i], bv[j], acc[i][j]);
    }
    __syncthreads();
  }

#pragma unroll
  for (int i = 0; i < 4; ++i)
#pragma unroll
    for (int j = 0; j < 4; ++j) {
      int c = (tx << 2) + j;
      yt[(ty << 2) + i][c] = acc[i][j] + bias[c];
    }
  __syncthreads();

  int r8 = tid >> 3, j8 = tid & 7;
  int rg = rb + r8;
  if (mode == 0) {
    float s = 0.f;
#pragma unroll
    for (int t = 0; t < 16; ++t) s += yt[r8][(j8 << 4) + t];
    s += __shfl_xor(s, 1); s += __shfl_xor(s, 2); s += __shfl_xor(s, 4);
    float mu = s * (1.0f / 128.0f);
    float vs = 0.f;
#pragma unroll
    for (int t = 0; t < 16; ++t) {
      float d = yt[r8][(j8 << 4) + t] - mu;
      vs = fmaf(d, d, vs);
    }
    vs += __shfl_xor(vs, 1); vs += __shfl_xor(vs, 2); vs += __shfl_xor(vs, 4);
    float var = vs * (1.0f / 128.0f);
    float rstd = 1.0f / sqrtf(var + 1e-5f);
    float q2p = 0.f;
#pragma unroll
    for (int t = 0; t < 16; ++t) {
      int c = (j8 << 4) + t;
      float qv = (yt[r8][c] - mu) * rstd * lng[c] + lnb[c];
      qout[(size_t)rg * D_ + c] = qv;
      q2p = fmaf(qv, qv, q2p);
    }
    q2p += __shfl_xor(q2p, 1); q2p += __shfl_xor(q2p, 2); q2p += __shfl_xor(q2p, 4);
    if (j8 == 0) q2out[rg] = q2p;
  } else {
    float s = 0.f;
#pragma unroll
    for (int t = 0; t < 16; ++t) {
      int c = (j8 << 4) + t;
      float v = yt[r8][c];
      v = v > 0.f ? v : 0.f;
      s = fmaf(v, v3s[c], s);
    }
    s += __shfl_xor(s, 1); s += __shfl_xor(s, 2); s += __shfl_xor(s, 4);
    if (j8 == 0) netout[rg] = s + c3[0];
  }
}

// ---------------- K0: k2[m] = sum_d mem_keys[m][d]^2 ---------------------------------
__global__ __launch_bounds__(256) void k0_keynorm(
    const float* __restrict__ keys, float* __restrict__ k2out)
{
  int m = blockIdx.x * 8 + (threadIdx.x >> 5);
  int l = threadIdx.x & 31;
  float4 a = *(const float4*)&keys[(size_t)m * D_ + (l << 2)];
  float s = a.x * a.x + a.y * a.y + a.z * a.z + a.w * a.w;
  s += __shfl_xor(s, 1); s += __shfl_xor(s, 2); s += __shfl_xor(s, 4);
  s += __shfl_xor(s, 8); s += __shfl_xor(s, 16);
  if (l == 0) k2out[m] = s;
}

// ---------------- K3: fused distance GEMM + per-(row,slice) exact top-50 -------------
__device__ __forceinline__ void sort128_wave(u64* sb, int lane) {
  for (int k = 2; k <= 128; k <<= 1)
    for (int j = k >> 1; j > 0; j >>= 1) {
#pragma unroll
      for (int half = 0; half < 2; ++half) {
        int e = lane + (half << 6);
        int p = e ^ j;
        if (p > e) {
          u64 x = sb[e], y = sb[p];
          bool up = ((e & k) == 0);
          if ((x > y) == up) { sb[e] = y; sb[p] = x; }
        }
      }
      __builtin_amdgcn_wave_barrier();
    }
}

__device__ void compact_block(
    bool final_, int rb, int slice, int tid,
    u64 (*sortbuf)[128], u64* thresh, int* cnt, u64* lbuf)
{
  int w = tid >> 6, lane = tid & 63;
  for (int rr = 0; rr < 8; ++rr) {
    int r = (w << 3) + rr;
    int c0 = cnt[r];
    if (!final_ && c0 <= CAP) continue;     // trigger only on overflow
    int valid = c0 < CAP ? c0 : CAP;
    u64* gb = &lbuf[(((size_t)(rb + r)) * NSLICE + slice) * CAP];
    u64 e0 = (lane < valid) ? gb[lane] : ~0ULL;
    u64 e1 = (lane + 64 < valid) ? gb[lane + 64] : ~0ULL;
    u64* sb = sortbuf[w];
    sb[lane] = e0; sb[lane + 64] = e1;
    __builtin_amdgcn_wave_barrier();
    sort128_wave(sb, lane);
    __builtin_amdgcn_wave_barrier();
    if (lane < KNN) gb[lane] = sb[lane];
    if (lane == 0) { cnt[r] = KNN; thresh[r] = sb[KNN - 1]; }
    __builtin_amdgcn_wave_barrier();
  }
}

__global__ __launch_bounds__(512) void k3_knn(
    const float* __restrict__ qg, const float* __restrict__ q2g,
    const float* __restrict__ keys, const float* __restrict__ k2g,
    u64* __restrict__ lbuf)
{
  __shared__ float qs[64][132];
  __shared__ float ks[64][64];
  __shared__ u64 sortbuf[8][128];
  __shared__ u64 thresh[64];
  __shared__ int cnt[64];
  __shared__ float q2s[64];
  __shared__ float k2s[64];
  __shared__ int ovf;

  int tid = threadIdx.x;
  int rb = blockIdx.x << 6;
  int slice = blockIdx.y;
  int m_start = slice * SLICE_LEN;
  int m_end = m_start + SLICE_LEN;

  {
    int r = tid >> 3, c16 = (tid & 7) << 4;
#pragma unroll
    for (int t = 0; t < 4; ++t)
      *(float4*)&qs[r][c16 + (t << 2)] =
          *(const float4*)&qg[(size_t)(rb + r) * D_ + c16 + (t << 2)];
  }
  if (tid < 64) {
    q2s[tid] = q2g[rb + tid];
    thresh[tid] = ~0ULL;
    cnt[tid] = 0;
  }
  if (tid == 0) ovf = 0;
  __syncthreads();

  int tx = tid & 15, ty = tid >> 4;   // tx 0..15 (cols), ty 0..31 (row pairs)

  for (int t0 = m_start; t0 < m_end; t0 += 64) {
    float acc[2][4] = {};
    for (int db = 0; db < D_; db += 64) {
      {
        int c = tid >> 3, d8 = (tid & 7) << 3;
        int m = t0 + c; if (m >= m_end) m = m_end - 1;   // clamp (masked later)
        const float* kp = &keys[(size_t)m * D_ + db + d8];
        float4 x = *(const float4*)kp;
        float4 y = *(const float4*)(kp + 4);
        ks[d8 + 0][c] = x.x; ks[d8 + 1][c] = x.y; ks[d8 + 2][c] = x.z; ks[d8 + 3][c] = x.w;
        ks[d8 + 4][c] = y.x; ks[d8 + 5][c] = y.y; ks[d8 + 6][c] = y.z; ks[d8 + 7][c] = y.w;
      }
      if (db == 0 && tid < 64) {
        int m = t0 + tid;
        k2s[tid] = (m < m_end) ? k2g[m] : 0.0f;
      }
      __syncthreads();
#pragma unroll 8
      for (int kk = 0; kk < 64; ++kk) {
        float4 b4 = *(const float4*)&ks[kk][tx << 2];
        float a0 = qs[ty][db + kk];
        float a1 = qs[ty + 32][db + kk];
        acc[0][0] = fmaf(a0, b4.x, acc[0][0]);
        acc[0][1] = fmaf(a0, b4.y, acc[0][1]);
        acc[0][2] = fmaf(a0, b4.z, acc[0][2]);
        acc[0][3] = fmaf(a0, b4.w, acc[0][3]);
        acc[1][0] = fmaf(a1, b4.x, acc[1][0]);
        acc[1][1] = fmaf(a1, b4.y, acc[1][1]);
        acc[1][2] = fmaf(a1, b4.z, acc[1][2]);
        acc[1][3] = fmaf(a1, b4.w, acc[1][3]);
      }
      __syncthreads();
    }

    // candidates: dist2 = q2 + k2 - 2*dot, key = (f32bits(dist)<<32)|idx
    u64 ck[2][4];
    bool pend[2][4];
#pragma unroll
    for (int i = 0; i < 2; ++i) {
      int r = ty + (i << 5);
      float q2v = q2s[r];
#pragma unroll
      for (int j = 0; j < 4; ++j) {
        int c = (tx << 2) + j;
        int m = t0 + c;
        float dd = q2v + k2s[c] - 2.0f * acc[i][j];
        ck[i][j] = ((u64)__float_as_uint(dd) << 32) | (u32)m;
        pend[i][j] = (m < m_end);
      }
    }

    for (;;) {
      if (tid == 0) ovf = 0;
      __syncthreads();
#pragma unroll
      for (int i = 0; i < 2; ++i) {
        int r = ty + (i << 5);
#pragma unroll
        for (int j = 0; j < 4; ++j) {
          if (pend[i][j]) {
            if (ck[i][j] < thresh[r]) {
              int pos = atomicAdd(&cnt[r], 1);
              if (pos < CAP) {
                lbuf[(((size_t)(rb + r)) * NSLICE + slice) * CAP + pos] = ck[i][j];
                pend[i][j] = false;
              } else {
                ovf = 1;            // benign race: all writers store 1
              }
            } else pend[i][j] = false;
          }
        }
      }
      __syncthreads();
      if (!ovf) break;
      __threadfence_block();
      compact_block(false, rb, slice, tid, sortbuf, thresh, cnt, lbuf);
      __syncthreads();
    }
  }

  __threadfence_block();
  compact_block(true, rb, slice, tid, sortbuf, thresh, cnt, lbuf);
}

// ---------------- K4: merge 8x50 per-slice winners -> exact top-50 -> output ---------
__global__ __launch_bounds__(64) void k4_merge(
    const u64* __restrict__ lbuf, const float* __restrict__ memv,
    const float* __restrict__ net, float* __restrict__ out)
{
  __shared__ u64 sb[512];
  int b = blockIdx.x, l = threadIdx.x;
#pragma unroll
  for (int h = 0; h < 8; ++h) {
    int e = l + (h << 6);
    u64 v = ~0ULL;
    if (e < NSLICE * KNN) {
      int s = e / KNN, j = e - s * KNN;
      v = lbuf[((size_t)b * NSLICE + s) * CAP + j];
    }
    sb[e] = v;
  }
  __syncthreads();
  for (int k = 2; k <= 512; k <<= 1)
    for (int j = k >> 1; j > 0; j >>= 1) {
#pragma unroll
      for (int h = 0; h < 8; ++h) {
        int e = l + (h << 6);
        int p = e ^ j;
        if (p > e) {
          u64 x = sb[e], y = sb[p];
          bool up = ((e & k) == 0);
          if ((x > y) == up) { sb[e] = y; sb[p] = x; }
        }
      }
      __builtin_amdgcn_wave_barrier();
    }
  __builtin_amdgcn_wave_barrier();
  float w = 0.f, wv = 0.f;
  if (l < KNN) {
    u64 key = sb[l];
    float d = __uint_as_float((u32)(key >> 32));
    u32 idx = (u32)key;
    float ww = 1.0f / (d + 1e-7f);
    w = ww;
    wv = ww * memv[idx];
  }
#pragma unroll
  for (int o = 1; o < 64; o <<= 1) {
    w += __shfl_xor(w, o);
    wv += __shfl_xor(wv, o);
  }
  if (l == 0) out[b] = 0.9f * (wv / w) + 0.1f * net[b];
}

// ---------------- launch --------------------------------------------------------------
extern "C" void kernel_launch(void* const* d_in, const int* in_sizes, int n_in,
                              void* d_out, int out_size, void* d_ws, size_t ws_size,
                              hipStream_t stream)
{
  const float* states     = (const float*)d_in[0];
  const float* W1         = (const float*)d_in[1];
  const float* b1         = (const float*)d_in[2];
  const float* W2         = (const float*)d_in[3];
  const float* b2         = (const float*)d_in[4];
  const float* lng        = (const float*)d_in[5];
  const float* lnb        = (const float*)d_in[6];
  const float* mem_keys   = (const float*)d_in[7];
  const float* mem_values = (const float*)d_in[8];
  const float* V1         = (const float*)d_in[9];
  const float* c1         = (const float*)d_in[10];
  const float* V2         = (const float*)d_in[11];
  const float* c2         = (const float*)d_in[12];
  const float* V3         = (const float*)d_in[13];
  const float* c3         = (const float*)d_in[14];
  float* out = (float*)d_out;

  char* ws = (char*)d_ws;
  float* h   = (float*)(ws + 0);            // 4 MB
  float* v1  = (float*)(ws + 4194304);      // 4 MB
  float* q   = (float*)(ws + 8388608);      // 2 MB
  float* q2  = (float*)(ws + 10485760);     // 16 KB
  float* net = (float*)(ws + 10502144);     // 16 KB
  float* k2g = (float*)(ws + 10518528);     // 200 KB
  u64*   lbuf = (u64*)(ws + 10719232);      // 32 MB

  k1_gemm<<<dim3(H_ / 64, B_ / 64, 2), 256, 0, stream>>>(states, W1, b1, V1, c1, h, v1);
  k2_fused<<<dim3(B_ / 32), 256, 0, stream>>>(0, h, W2, b2, lng, lnb, V3, c3, q, q2, net);
  k2_fused<<<dim3(B_ / 32), 256, 0, stream>>>(1, v1, V2, c2, lng, lnb, V3, c3, q, q2, net);
  k0_keynorm<<<dim3(M_ / 8), 256, 0, stream>>>(mem_keys, k2g);
  k3_knn<<<dim3(B_ / 64, NSLICE), 512, 0, stream>>>(q, q2, mem_keys, k2g, lbuf);
  k4_merge<<<dim3(B_), 64, 0, stream>>>(lbuf, mem_values, net, out);
}

// Round 2
// 1611.407 us; speedup vs baseline: 1.0856x; 1.0856x over previous
//
#include <hip/hip_runtime.h>
#include <stdint.h>

#define B_   4096
#define S_   544
#define H_   256
#define D_   128
#define M_   50000
#define KNN  50
#define NSLICE 8
#define SLICE_LEN (M_ / NSLICE)   // 6250
#define CAP  128
#define TN   128                  // keys per k3 tile

typedef unsigned long long u64;
typedef unsigned int u32;

// ---------------- K1: h = relu(states@W1+b1) (z=0), v1 = relu(states@V1+c1) (z=1) ----
__global__ __launch_bounds__(256) void k1_gemm(
    const float* __restrict__ A,
    const float* __restrict__ W1, const float* __restrict__ b1,
    const float* __restrict__ V1, const float* __restrict__ c1,
    float* __restrict__ hout, float* __restrict__ v1out)
{
  const float* W    = (blockIdx.z == 0) ? W1 : V1;
  const float* bias = (blockIdx.z == 0) ? b1 : c1;
  float* out        = (blockIdx.z == 0) ? hout : v1out;

  __shared__ float as[16][68];
  __shared__ float bs[16][64];

  int tid = threadIdx.x;
  int tx = tid & 15, ty = tid >> 4;
  int rb = blockIdx.y * 64, cb = blockIdx.x * 64;

  float acc[4][4] = {};

  for (int k0 = 0; k0 < S_; k0 += 16) {
    {
      int r = tid >> 2, k4 = (tid & 3) << 2;
      float4 a = *(const float4*)&A[(size_t)(rb + r) * S_ + k0 + k4];
      as[k4 + 0][r] = a.x; as[k4 + 1][r] = a.y;
      as[k4 + 2][r] = a.z; as[k4 + 3][r] = a.w;
    }
    {
      int kk = tid >> 4, c4 = (tid & 15) << 2;
      *(float4*)&bs[kk][c4] = *(const float4*)&W[(size_t)(k0 + kk) * H_ + cb + c4];
    }
    __syncthreads();
#pragma unroll
    for (int kk = 0; kk < 16; ++kk) {
      float4 a4 = *(const float4*)&as[kk][ty << 2];
      float4 b4 = *(const float4*)&bs[kk][tx << 2];
      float av[4] = {a4.x, a4.y, a4.z, a4.w};
      float bv[4] = {b4.x, b4.y, b4.z, b4.w};
#pragma unroll
      for (int i = 0; i < 4; ++i)
#pragma unroll
        for (int j = 0; j < 4; ++j)
          acc[i][j] = fmaf(av[i], bv[j], acc[i][j]);
    }
    __syncthreads();
  }

#pragma unroll
  for (int i = 0; i < 4; ++i) {
    int r = rb + (ty << 2) + i;
#pragma unroll
    for (int j = 0; j < 4; ++j) {
      int c = cb + (tx << 2) + j;
      float v = acc[i][j] + bias[c];
      out[(size_t)r * H_ + c] = v > 0.0f ? v : 0.0f;
    }
  }
}

// ---------------- K2: mode 0: q = LN(h@W2+b2), q2 = sum(q*q)
//                      mode 1: v2 = relu(v1@V2+c2); net = v2@V3 + c3 ------------------
__global__ __launch_bounds__(256) void k2_fused(
    int mode,
    const float* __restrict__ A,      // [B_][H_]
    const float* __restrict__ W,      // [H_][D_]
    const float* __restrict__ bias,   // [D_]
    const float* __restrict__ lng, const float* __restrict__ lnb,
    const float* __restrict__ V3, const float* __restrict__ c3,
    float* __restrict__ qout, float* __restrict__ q2out,
    float* __restrict__ netout)
{
  __shared__ float as[32][36];
  __shared__ float bs[32][132];
  __shared__ float yt[32][132];
  __shared__ float v3s[128];

  int tid = threadIdx.x;
  int tx = tid & 31, ty = tid >> 5;
  int rb = blockIdx.x * 32;

  if (mode == 1 && tid < 128) v3s[tid] = V3[tid];

  float acc[4][4] = {};

  for (int k0 = 0; k0 < H_; k0 += 32) {
    {
      int r = tid >> 3, k4 = (tid & 7) << 2;
      float4 a = *(const float4*)&A[(size_t)(rb + r) * H_ + k0 + k4];
      as[k4 + 0][r] = a.x; as[k4 + 1][r] = a.y;
      as[k4 + 2][r] = a.z; as[k4 + 3][r] = a.w;
    }
    {
      int kk = tid >> 3, c16 = (tid & 7) << 4;
#pragma unroll
      for (int t = 0; t < 4; ++t)
        *(float4*)&bs[kk][c16 + (t << 2)] =
            *(const float4*)&W[(size_t)(k0 + kk) * D_ + c16 + (t << 2)];
    }
    __syncthreads();
#pragma unroll
    for (int kk = 0; kk < 32; ++kk) {
      float4 a4 = *(const float4*)&as[kk][ty << 2];
      float4 b4 = *(const float4*)&bs[kk][tx << 2];
      float av[4] = {a4.x, a4.y, a4.z, a4.w};
      float bv[4] = {b4.x, b4.y, b4.z, b4.w};
#pragma unroll
      for (int i = 0; i < 4; ++i)
#pragma unroll
        for (int j = 0; j < 4; ++j)
          acc[i][j] = fmaf(av[i], bv[j], acc[i][j]);
    }
    __syncthreads();
  }

#pragma unroll
  for (int i = 0; i < 4; ++i)
#pragma unroll
    for (int j = 0; j < 4; ++j) {
      int c = (tx << 2) + j;
      yt[(ty << 2) + i][c] = acc[i][j] + bias[c];
    }
  __syncthreads();

  int r8 = tid >> 3, j8 = tid & 7;
  int rg = rb + r8;
  if (mode == 0) {
    float s = 0.f;
#pragma unroll
    for (int t = 0; t < 16; ++t) s += yt[r8][(j8 << 4) + t];
    s += __shfl_xor(s, 1); s += __shfl_xor(s, 2); s += __shfl_xor(s, 4);
    float mu = s * (1.0f / 128.0f);
    float vs = 0.f;
#pragma unroll
    for (int t = 0; t < 16; ++t) {
      float d = yt[r8][(j8 << 4) + t] - mu;
      vs = fmaf(d, d, vs);
    }
    vs += __shfl_xor(vs, 1); vs += __shfl_xor(vs, 2); vs += __shfl_xor(vs, 4);
    float var = vs * (1.0f / 128.0f);
    float rstd = 1.0f / sqrtf(var + 1e-5f);
    float q2p = 0.f;
#pragma unroll
    for (int t = 0; t < 16; ++t) {
      int c = (j8 << 4) + t;
      float qv = (yt[r8][c] - mu) * rstd * lng[c] + lnb[c];
      qout[(size_t)rg * D_ + c] = qv;
      q2p = fmaf(qv, qv, q2p);
    }
    q2p += __shfl_xor(q2p, 1); q2p += __shfl_xor(q2p, 2); q2p += __shfl_xor(q2p, 4);
    if (j8 == 0) q2out[rg] = q2p;
  } else {
    float s = 0.f;
#pragma unroll
    for (int t = 0; t < 16; ++t) {
      int c = (j8 << 4) + t;
      float v = yt[r8][c];
      v = v > 0.f ? v : 0.f;
      s = fmaf(v, v3s[c], s);
    }
    s += __shfl_xor(s, 1); s += __shfl_xor(s, 2); s += __shfl_xor(s, 4);
    if (j8 == 0) netout[rg] = s + c3[0];
  }
}

// ---------------- K0: k2[m] = sum_d mem_keys[m][d]^2 ---------------------------------
__global__ __launch_bounds__(256) void k0_keynorm(
    const float* __restrict__ keys, float* __restrict__ k2out)
{
  int m = blockIdx.x * 8 + (threadIdx.x >> 5);
  int l = threadIdx.x & 31;
  float4 a = *(const float4*)&keys[(size_t)m * D_ + (l << 2)];
  float s = a.x * a.x + a.y * a.y + a.z * a.z + a.w * a.w;
  s += __shfl_xor(s, 1); s += __shfl_xor(s, 2); s += __shfl_xor(s, 4);
  s += __shfl_xor(s, 8); s += __shfl_xor(s, 16);
  if (l == 0) k2out[m] = s;
}

// ---------------- K3: fused distance GEMM + per-(row,slice) exact top-50 -------------
__device__ __forceinline__ void sort128_wave(u64* sb, int lane) {
  for (int k = 2; k <= 128; k <<= 1)
    for (int j = k >> 1; j > 0; j >>= 1) {
#pragma unroll
      for (int half = 0; half < 2; ++half) {
        int e = lane + (half << 6);
        int p = e ^ j;
        if (p > e) {
          u64 x = sb[e], y = sb[p];
          bool up = ((e & k) == 0);
          if ((x > y) == up) { sb[e] = y; sb[p] = x; }
        }
      }
      __builtin_amdgcn_wave_barrier();
    }
}

// 4 waves, each handles 16 rows
__device__ void compact_block(
    bool final_, int rb, int slice, int tid,
    u64 (*sortbuf)[128], u64* thresh, int* cnt, u64* lbuf)
{
  int w = tid >> 6, lane = tid & 63;
  for (int rr = 0; rr < 16; ++rr) {
    int r = (w << 4) + rr;
    int c0 = cnt[r];
    if (!final_ && c0 <= CAP) continue;     // trigger only on overflow
    int valid = c0 < CAP ? c0 : CAP;
    u64* gb = &lbuf[(((size_t)(rb + r)) * NSLICE + slice) * CAP];
    u64 e0 = (lane < valid) ? gb[lane] : ~0ULL;
    u64 e1 = (lane + 64 < valid) ? gb[lane + 64] : ~0ULL;
    u64* sb = sortbuf[w];
    sb[lane] = e0; sb[lane + 64] = e1;
    __builtin_amdgcn_wave_barrier();
    sort128_wave(sb, lane);
    __builtin_amdgcn_wave_barrier();
    if (lane < KNN) gb[lane] = sb[lane];
    if (lane == 0) { cnt[r] = KNN; thresh[r] = sb[KNN - 1]; }
    __builtin_amdgcn_wave_barrier();
  }
}

__global__ __launch_bounds__(256) void k3_knn(
    const float* __restrict__ qg, const float* __restrict__ q2g,
    const float* __restrict__ keys, const float* __restrict__ k2g,
    u64* __restrict__ lbuf)
{
  __shared__ float qs[128][68];     // [dim][row], padded
  __shared__ float ks[64][128];     // [dim-chunk][key]
  __shared__ u64 sortbuf[4][128];
  __shared__ u64 thresh[64];
  __shared__ int cnt[64];
  __shared__ float q2s[64];
  __shared__ float k2s[128];
  __shared__ int ovf;

  int tid = threadIdx.x;
  int rb = blockIdx.x << 6;
  int slice = blockIdx.y;
  int m_start = slice * SLICE_LEN;
  int m_end = m_start + SLICE_LEN;

  // stage q panel transposed: qs[d][r]
  {
    int r = tid & 63, d0 = (tid >> 6) << 5;
#pragma unroll
    for (int t = 0; t < 8; ++t) {
      float4 a = *(const float4*)&qg[(size_t)(rb + r) * D_ + d0 + (t << 2)];
      int d = d0 + (t << 2);
      qs[d + 0][r] = a.x; qs[d + 1][r] = a.y;
      qs[d + 2][r] = a.z; qs[d + 3][r] = a.w;
    }
  }
  if (tid < 64) {
    q2s[tid] = q2g[rb + tid];
    thresh[tid] = ~0ULL;
    cnt[tid] = 0;
  }
  if (tid == 0) ovf = 0;
  __syncthreads();

  int tx = tid & 15, ty = tid >> 4;   // tx: 8 keys (4+4 split), ty: 4 rows

  for (int t0 = m_start; t0 < m_end; t0 += TN) {
    float acc[4][8] = {};
    for (int db = 0; db < D_; db += 64) {
      {
        int m = tid >> 1, d0 = (tid & 1) << 5;
        int mg = t0 + m; if (mg > m_end - 1) mg = m_end - 1;  // clamp (masked later)
        const float* kp = &keys[(size_t)mg * D_ + db + d0];
#pragma unroll
        for (int t = 0; t < 8; ++t) {
          float4 x = *(const float4*)(kp + (t << 2));
          int d = d0 + (t << 2);
          ks[d + 0][m] = x.x; ks[d + 1][m] = x.y;
          ks[d + 2][m] = x.z; ks[d + 3][m] = x.w;
        }
      }
      if (db == 0 && tid < 128) {
        int mg = t0 + tid;
        k2s[tid] = (mg < m_end) ? k2g[mg] : 0.0f;
      }
      __syncthreads();
#pragma unroll 4
      for (int kk = 0; kk < 64; ++kk) {
        float4 a4 = *(const float4*)&qs[db + kk][ty << 2];
        float4 b4a = *(const float4*)&ks[kk][tx << 2];
        float4 b4b = *(const float4*)&ks[kk][64 + (tx << 2)];
        float av[4] = {a4.x, a4.y, a4.z, a4.w};
        float bv[8] = {b4a.x, b4a.y, b4a.z, b4a.w, b4b.x, b4b.y, b4b.z, b4b.w};
#pragma unroll
        for (int i = 0; i < 4; ++i)
#pragma unroll
          for (int j = 0; j < 8; ++j)
            acc[i][j] = fmaf(av[i], bv[j], acc[i][j]);
      }
      __syncthreads();
    }

    // selection: 32 candidates per thread, pend tracked as bitmask
    u32 pend = 0;
#pragma unroll
    for (int i = 0; i < 4; ++i)
#pragma unroll
      for (int j = 0; j < 8; ++j) {
        int c = (j < 4) ? ((tx << 2) + j) : (64 + (tx << 2) + (j - 4));
        if (t0 + c < m_end) pend |= (1u << ((i << 3) | j));
      }

    for (;;) {
      if (tid == 0) ovf = 0;
      __syncthreads();
      if (pend) {
#pragma unroll
        for (int i = 0; i < 4; ++i) {
          int r = (ty << 2) + i;
          float q2v = q2s[r];
#pragma unroll
          for (int j = 0; j < 8; ++j) {
            u32 bit = 1u << ((i << 3) | j);
            if (pend & bit) {
              int c = (j < 4) ? ((tx << 2) + j) : (64 + (tx << 2) + (j - 4));
              float dd = q2v + k2s[c] - 2.0f * acc[i][j];
              u64 ck = ((u64)__float_as_uint(dd) << 32) | (u32)(t0 + c);
              if (ck < thresh[r]) {
                int pos = atomicAdd(&cnt[r], 1);
                if (pos < CAP) {
                  lbuf[(((size_t)(rb + r)) * NSLICE + slice) * CAP + pos] = ck;
                  pend &= ~bit;
                } else {
                  ovf = 1;          // benign race: all writers store 1
                }
              } else pend &= ~bit;
            }
          }
        }
      }
      __syncthreads();
      if (!ovf) break;
      __threadfence_block();
      compact_block(false, rb, slice, tid, sortbuf, thresh, cnt, lbuf);
      __syncthreads();
    }
  }

  __threadfence_block();
  compact_block(true, rb, slice, tid, sortbuf, thresh, cnt, lbuf);
}

// ---------------- K4: merge 8x50 per-slice winners -> exact top-50 -> output ---------
__global__ __launch_bounds__(64) void k4_merge(
    const u64* __restrict__ lbuf, const float* __restrict__ memv,
    const float* __restrict__ net, float* __restrict__ out)
{
  __shared__ u64 sb[512];
  int b = blockIdx.x, l = threadIdx.x;
#pragma unroll
  for (int h = 0; h < 8; ++h) {
    int e = l + (h << 6);
    u64 v = ~0ULL;
    if (e < NSLICE * KNN) {
      int s = e / KNN, j = e - s * KNN;
      v = lbuf[((size_t)b * NSLICE + s) * CAP + j];
    }
    sb[e] = v;
  }
  __syncthreads();
  for (int k = 2; k <= 512; k <<= 1)
    for (int j = k >> 1; j > 0; j >>= 1) {
#pragma unroll
      for (int h = 0; h < 8; ++h) {
        int e = l + (h << 6);
        int p = e ^ j;
        if (p > e) {
          u64 x = sb[e], y = sb[p];
          bool up = ((e & k) == 0);
          if ((x > y) == up) { sb[e] = y; sb[p] = x; }
        }
      }
      __builtin_amdgcn_wave_barrier();
    }
  __builtin_amdgcn_wave_barrier();
  float w = 0.f, wv = 0.f;
  if (l < KNN) {
    u64 key = sb[l];
    float d = __uint_as_float((u32)(key >> 32));
    u32 idx = (u32)key;
    float ww = 1.0f / (d + 1e-7f);
    w = ww;
    wv = ww * memv[idx];
  }
#pragma unroll
  for (int o = 1; o < 64; o <<= 1) {
    w += __shfl_xor(w, o);
    wv += __shfl_xor(wv, o);
  }
  if (l == 0) out[b] = 0.9f * (wv / w) + 0.1f * net[b];
}

// ---------------- launch --------------------------------------------------------------
extern "C" void kernel_launch(void* const* d_in, const int* in_sizes, int n_in,
                              void* d_out, int out_size, void* d_ws, size_t ws_size,
                              hipStream_t stream)
{
  const float* states     = (const float*)d_in[0];
  const float* W1         = (const float*)d_in[1];
  const float* b1         = (const float*)d_in[2];
  const float* W2         = (const float*)d_in[3];
  const float* b2         = (const float*)d_in[4];
  const float* lng        = (const float*)d_in[5];
  const float* lnb        = (const float*)d_in[6];
  const float* mem_keys   = (const float*)d_in[7];
  const float* mem_values = (const float*)d_in[8];
  const float* V1         = (const float*)d_in[9];
  const float* c1         = (const float*)d_in[10];
  const float* V2         = (const float*)d_in[11];
  const float* c2         = (const float*)d_in[12];
  const float* V3         = (const float*)d_in[13];
  const float* c3         = (const float*)d_in[14];
  float* out = (float*)d_out;

  char* ws = (char*)d_ws;
  float* h   = (float*)(ws + 0);            // 4 MB
  float* v1  = (float*)(ws + 4194304);      // 4 MB
  float* q   = (float*)(ws + 8388608);      // 2 MB
  float* q2  = (float*)(ws + 10485760);     // 16 KB
  float* net = (float*)(ws + 10502144);     // 16 KB
  float* k2g = (float*)(ws + 10518528);     // 200 KB
  u64*   lbuf = (u64*)(ws + 10719232);      // 32 MB

  k1_gemm<<<dim3(H_ / 64, B_ / 64, 2), 256, 0, stream>>>(states, W1, b1, V1, c1, h, v1);
  k2_fused<<<dim3(B_ / 32), 256, 0, stream>>>(0, h, W2, b2, lng, lnb, V3, c3, q, q2, net);
  k2_fused<<<dim3(B_ / 32), 256, 0, stream>>>(1, v1, V2, c2, lng, lnb, V3, c3, q, q2, net);
  k0_keynorm<<<dim3(M_ / 8), 256, 0, stream>>>(mem_keys, k2g);
  k3_knn<<<dim3(B_ / 64, NSLICE), 256, 0, stream>>>(q, q2, mem_keys, k2g, lbuf);
  k4_merge<<<dim3(B_), 64, 0, stream>>>(lbuf, mem_values, net, out);
}